// Round 5
// baseline (743.432 us; speedup 1.0000x reference)
//
#include <hip/hip_runtime.h>
#include <hip/hip_bf16.h>

#define T_LEN 2048
#define HID_DIM 2048
#define NH 16
#define NKV 2
#define HD 256
#define ROT 64
#define EPS_F 1e-6f
#define SCALE_F 0.0625f   // 256^-0.5
#define THETA_F 10000000.0f

typedef __bf16 bf16x8 __attribute__((ext_vector_type(8)));
typedef float floatx4 __attribute__((ext_vector_type(4)));
typedef unsigned short ushort8v __attribute__((ext_vector_type(8)));

__device__ __forceinline__ unsigned short f2bf(float x) {
  unsigned int u = __float_as_uint(x);
  unsigned int rounding = 0x7FFFu + ((u >> 16) & 1u);
  return (unsigned short)((u + rounding) >> 16);
}
__device__ __forceinline__ float bf2f(unsigned short u) {
  return __uint_as_float(((unsigned int)u) << 16);
}
__device__ __forceinline__ floatx4 mfma16(bf16x8 a, bf16x8 b, floatx4 c) {
  return __builtin_amdgcn_mfma_f32_16x16x32_bf16(a, b, c, 0, 0, 0);
}
// async global->LDS DMA, 16B/lane (used in GEMM only; barriers drain it there by design)
__device__ __forceinline__ void gl_lds16(const unsigned short* g, unsigned short* l) {
  __builtin_amdgcn_global_load_lds(
      (const __attribute__((address_space(1))) unsigned int*)g,
      (__attribute__((address_space(3))) unsigned int*)l, 16, 0, 0);
}

// ---------------- merged fp32 -> bf16 conversion (5 segments, f4-vectorized) ----------------
__global__ __launch_bounds__(256) void cvt_all(
    const float* __restrict__ hs, const float* __restrict__ wq,
    const float* __restrict__ wk, const float* __restrict__ wv,
    const float* __restrict__ wo, unsigned short* __restrict__ hsb,
    unsigned short* __restrict__ qkvwb, unsigned short* __restrict__ wob) {
  int i = blockIdx.x * 256 + threadIdx.x;  // float4 index, total 7864320
  const float4* s4;
  ushort4* d4;
  int j;
  if (i < 1048576) { s4 = (const float4*)hs; d4 = (ushort4*)hsb; j = i; }
  else if (i < 5242880) { s4 = (const float4*)wq; d4 = (ushort4*)qkvwb; j = i - 1048576; }
  else if (i < 5505024) { s4 = (const float4*)wk; d4 = (ushort4*)qkvwb + 4194304; j = i - 5242880; }
  else if (i < 5767168) { s4 = (const float4*)wv; d4 = (ushort4*)qkvwb + 4456448; j = i - 5505024; }
  else { s4 = (const float4*)wo; d4 = (ushort4*)wob; j = i - 5767168; }
  float4 v = s4[j];
  ushort4 o;
  o.x = f2bf(v.x); o.y = f2bf(v.y); o.z = f2bf(v.z); o.w = f2bf(v.w);
  d4[j] = o;
}

// ---------------- bf16 GEMM: C[M,N] = A[M,K] * B[N,K]^T ----------------
__global__ __launch_bounds__(256) void gemm_bf16_bt(
    const unsigned short* __restrict__ A,
    const unsigned short* __restrict__ B,
    void* __restrict__ Cv, int M, int N, int K, int c_bf16) {
  __shared__ alignas(16) unsigned short As[128 * 32];
  __shared__ alignas(16) unsigned short Bs[128 * 32];
  const int tid = threadIdx.x;
  const int m0 = blockIdx.y * 128;
  const int n0 = blockIdx.x * 128;
  const int lane = tid & 63;
  const int wave = tid >> 6;
  const int wm = (wave >> 1) * 64;
  const int wn = (wave & 1) * 64;
  const int lrow = lane & 15;
  const int kgrp = lane >> 4;

  const unsigned short* aG = A + (size_t)(m0 + wave * 32 + (lane >> 2)) * K + (lane & 3) * 8;
  const unsigned short* bG = B + (size_t)(n0 + wave * 32 + (lane >> 2)) * K + (lane & 3) * 8;
  unsigned short* aL0 = &As[(wave * 32) * 32];
  unsigned short* aL1 = &As[(wave * 32 + 16) * 32];
  unsigned short* bL0 = &Bs[(wave * 32) * 32];
  unsigned short* bL1 = &Bs[(wave * 32 + 16) * 32];

  floatx4 acc[4][4];
#pragma unroll
  for (int i = 0; i < 4; i++)
#pragma unroll
    for (int j = 0; j < 4; j++) acc[i][j] = floatx4{0.f, 0.f, 0.f, 0.f};

  for (int k0 = 0; k0 < K; k0 += 32) {
    gl_lds16(aG + k0, aL0);
    gl_lds16(aG + (size_t)16 * K + k0, aL1);
    gl_lds16(bG + k0, bL0);
    gl_lds16(bG + (size_t)16 * K + k0, bL1);
    __syncthreads();
    bf16x8 af[4], bfr[4];
#pragma unroll
    for (int i = 0; i < 4; i++)
      af[i] = *reinterpret_cast<const bf16x8*>(&As[(wm + i * 16 + lrow) * 32 + kgrp * 8]);
#pragma unroll
    for (int j = 0; j < 4; j++)
      bfr[j] = *reinterpret_cast<const bf16x8*>(&Bs[(wn + j * 16 + lrow) * 32 + kgrp * 8]);
#pragma unroll
    for (int i = 0; i < 4; i++)
#pragma unroll
      for (int j = 0; j < 4; j++)
        acc[i][j] = mfma16(af[i], bfr[j], acc[i][j]);
    __syncthreads();
  }

  if (c_bf16) {
    unsigned short* C = (unsigned short*)Cv;
#pragma unroll
    for (int i = 0; i < 4; i++) {
      int row = m0 + wm + i * 16 + kgrp * 4;
#pragma unroll
      for (int j = 0; j < 4; j++) {
        int col = n0 + wn + j * 16 + lrow;
#pragma unroll
        for (int r = 0; r < 4; r++)
          C[(size_t)(row + r) * N + col] = f2bf(acc[i][j][r]);
      }
    }
  } else {
    float* C = (float*)Cv;
#pragma unroll
    for (int i = 0; i < 4; i++) {
      int row = m0 + wm + i * 16 + kgrp * 4;
#pragma unroll
      for (int j = 0; j < 4; j++) {
        int col = n0 + wn + j * 16 + lrow;
#pragma unroll
        for (int r = 0; r < 4; r++)
          C[(size_t)(row + r) * N + col] = acc[i][j][r];
      }
    }
  }
}

// ---------------- RMSNorm + partial RoPE (per (t, head), D=256) ----------------
__global__ __launch_bounds__(256) void norm_rope(
    const unsigned short* __restrict__ in, const float* __restrict__ w,
    const int* __restrict__ pos, unsigned short* __restrict__ outb,
    int in_rs, int in_hs, int out_rs) {
  const int t = blockIdx.x, h = blockIdx.y, d = threadIdx.x;
  float x = bf2f(in[(size_t)t * in_rs + h * in_hs + d]);
  float ss = x * x;
#pragma unroll
  for (int m = 32; m >= 1; m >>= 1) ss += __shfl_xor(ss, m);
  __shared__ float wsum[4];
  if ((d & 63) == 0) wsum[d >> 6] = ss;
  __syncthreads();
  float tot = (wsum[0] + wsum[1]) + (wsum[2] + wsum[3]);
  float rms = rsqrtf(tot * (1.0f / 256.0f) + EPS_F);
  float y = x * rms * (1.0f + w[d]);
  float o = y;
  if (d < ROT) {
    float partner = __shfl_xor(y, ROT / 2);
    int i = d & (ROT / 2 - 1);
    // theta^(-i/32) = 2^(-i*log2(theta)/32), log2(1e7)=23.2534966642
    float fr = (float)pos[t] * exp2f(-(float)i * (23.2534966642f / 32.0f));
    float c = cosf(fr), s = sinf(fr);
    o = (d < ROT / 2) ? (y * c - partner * s) : (partner * s + y * c);
  }
  outb[(size_t)t * out_rs + h * HD + d] = f2bf(o);
}

// ---------------- V transpose: (T, cols src_off..+512) -> (512, T) ----------------
__global__ __launch_bounds__(256) void vtrans(
    const unsigned short* __restrict__ vin, unsigned short* __restrict__ vT,
    int src_stride, int src_off) {
  int gid = blockIdx.x * 256 + threadIdx.x;  // gid = c*T + t
  int t = gid & (T_LEN - 1);
  int c = gid >> 11;
  vT[gid] = vin[(size_t)t * src_stride + src_off + c];
}

// ---------------- Flash attention v5: register-staged K/V pipeline ----------------
// Block 512 thr (8 waves), grid (16 pairs, 16 heads). Wave (w3=wv&3, half=wv>>2):
// rows w3*16 of paired tiles (p, 31-p); half h covers 32-key chunk kb64+h*32.
// K/V(ib+1) prefetched global->VGPR during slab ib compute; committed to LDS
// via ds_write between barriers (vmcnt wait at use point => latency hidden,
// unlike global_load_lds whose DMA is drained by every barrier).
__global__ __launch_bounds__(512, 2) void attn_fwd(
    const unsigned short* __restrict__ qbf,    // (T, H*D) post norm+rope
    const unsigned short* __restrict__ kbf,    // (T, KV*D) post norm+rope
    const unsigned short* __restrict__ vT,     // (KV*D, T)
    const unsigned short* __restrict__ qkvout, // (T, 9216), gate at h*512+256
    unsigned short* __restrict__ og)           // (T, H*D)
{
  const int p = blockIdx.x;
  const int h = blockIdx.y;
  const int wv = threadIdx.x >> 6;
  const int w3 = wv & 3;
  const int half = wv >> 2;
  const int lane = threadIdx.x & 63;
  const int lrow = lane & 15;
  const int kgrp = lane >> 4;
  const int kvh = h >> 3;  // H/KV = 8
  const int tB = 31 - p;
  const int q0A = p * 64 + w3 * 16;
  const int q0B = tB * 64 + w3 * 16;
  const int nb = tB + 1;  // 64-key slabs

  // LDS: Ks 32KB | Vs 32KB | Ps 20KB = 84KB. Combine overlays Obuf on Ks+Vs.
  __shared__ alignas(16) unsigned char SMEM[86016];
  unsigned short* Ks = (unsigned short*)SMEM;            // [key 0..63][256 d], chunk^=(key&7)
  unsigned short* Vs = (unsigned short*)(SMEM + 32768);  // [dim 0..255][64 k], chunk^=(dim&7)
  unsigned short* Ps = (unsigned short*)(SMEM + 65536) + wv * 1280;  // 2 tiles x 16 x 40
  float* Obuf = (float*)SMEM;
  float* Lbuf = (float*)(SMEM + 65536);

  // ---- staging address precompute (lane-constant over the loop) ----
  const unsigned short* kgsrc[4];
  const unsigned short* vgsrc[4];
  unsigned short* kldst[4];
  unsigned short* vldst[4];
#pragma unroll
  for (int i = 0; i < 4; ++i) {
    const int inst = wv * 4 + i;
    const int key = inst * 2 + (lane >> 5);
    const int kc = lane & 31;
    kgsrc[i] = kbf + (size_t)key * (NKV * HD) + kvh * HD + kc * 8;
    kldst[i] = Ks + key * 256 + ((kc ^ (key & 7)) * 8);
    const int dim = inst * 8 + (lane >> 3);
    const int vc = lane & 7;
    vgsrc[i] = vT + (size_t)(kvh * HD + dim) * T_LEN + vc * 8;
    vldst[i] = Vs + dim * 64 + ((vc ^ (dim & 7)) * 8);
  }

  // qaB resident (tile B is active every slab); qaA reloaded per active slab.
  const unsigned short* qrA = qbf + (size_t)(q0A + lrow) * (NH * HD) + h * HD + kgrp * 8;
  const unsigned short* qrB = qbf + (size_t)(q0B + lrow) * (NH * HD) + h * HD + kgrp * 8;
  bf16x8 qaB[8];
#pragma unroll
  for (int s = 0; s < 8; s++) qaB[s] = *reinterpret_cast<const bf16x8*>(qrB + s * 32);

  float lpA[4] = {0.f, 0.f, 0.f, 0.f}, lpB[4] = {0.f, 0.f, 0.f, 0.f};
  floatx4 oA[16], oB[16];
#pragma unroll
  for (int dt = 0; dt < 16; dt++) { oA[dt] = floatx4{0.f,0.f,0.f,0.f}; oB[dt] = floatx4{0.f,0.f,0.f,0.f}; }

  // prologue: prefetch slab 0 into regs
  ushort8v kpre[4], vpre[4];
#pragma unroll
  for (int i = 0; i < 4; ++i) {
    kpre[i] = *reinterpret_cast<const ushort8v*>(kgsrc[i]);
    vpre[i] = *reinterpret_cast<const ushort8v*>(vgsrc[i]);
  }

  for (int ib = 0; ib < nb; ++ib) {
    const int kb64 = ib * 64;
    const int kb = kb64 + half * 32;  // this wave's 32-key chunk
    const bool dA = kb <= q0A + 15;
    const bool dB = kb <= q0B + 15;

    // issue qaA reload early: barrier + ds_write phase hides most L2 latency
    bf16x8 qaA[8];
    if (dA) {
#pragma unroll
      for (int s = 0; s < 8; s++) qaA[s] = *reinterpret_cast<const bf16x8*>(qrA + s * 32);
    }

    __syncthreads();  // all waves done reading Ks/Vs of slab ib-1
    // commit prefetched regs to LDS (vmcnt waits happen here, ~1 slab after issue)
#pragma unroll
    for (int i = 0; i < 4; ++i) *reinterpret_cast<ushort8v*>(kldst[i]) = kpre[i];
#pragma unroll
    for (int i = 0; i < 4; ++i) *reinterpret_cast<ushort8v*>(vldst[i]) = vpre[i];
    __syncthreads();  // Ks/Vs(ib) ready

    // prefetch slab ib+1 (plain global loads — cross barriers freely)
    if (ib + 1 < nb) {
      const size_t ko = (size_t)(kb64 + 64) * (NKV * HD);
#pragma unroll
      for (int i = 0; i < 4; ++i) {
        kpre[i] = *reinterpret_cast<const ushort8v*>(kgsrc[i] + ko);
        vpre[i] = *reinterpret_cast<const ushort8v*>(vgsrc[i] + kb64 + 64);
      }
    }

    // ---- S = Q K^T over 2 j-subtiles of 16 keys ----
    floatx4 sA[2], sB[2];
#pragma unroll
    for (int j = 0; j < 2; j++) { sA[j] = floatx4{0.f,0.f,0.f,0.f}; sB[j] = floatx4{0.f,0.f,0.f,0.f}; }
    const unsigned short* kbase = Ks + (half * 32) * 256;
#pragma unroll
    for (int j = 0; j < 2; ++j) {
      const int ks = kb + j * 16;
      const bool nA = dA && (ks <= q0A + 15);
      const bool nB = dB && (ks <= q0B + 15);
      if (!(nA || nB)) continue;
#pragma unroll
      for (int s = 0; s < 8; s++) {
        bf16x8 kf = *reinterpret_cast<const bf16x8*>(
            &kbase[(j * 16 + lrow) * 256 + (((s * 4 + kgrp) ^ (lrow & 7)) * 8)]);
        if (nA) sA[j] = mfma16(qaA[s], kf, sA[j]);
        if (nB) sB[j] = mfma16(qaB[s], kf, sB[j]);
      }
    }

    // ---- P = exp(S*scale), causal mask, no max subtraction (|s|<=16 bounded) ----
    if (dA) {
#pragma unroll
      for (int r = 0; r < 4; ++r) {
        const int qr = q0A + kgrp * 4 + r;
        float p0 = (kb + lrow <= qr) ? __expf(sA[0][r] * SCALE_F) : 0.f;
        float p1 = (kb + 16 + lrow <= qr) ? __expf(sA[1][r] * SCALE_F) : 0.f;
        lpA[r] += p0 + p1;
        Ps[(kgrp * 4 + r) * 40 + lrow] = f2bf(p0);
        Ps[(kgrp * 4 + r) * 40 + 16 + lrow] = f2bf(p1);
      }
    }
    if (dB) {
#pragma unroll
      for (int r = 0; r < 4; ++r) {
        const int qr = q0B + kgrp * 4 + r;
        float p0 = (kb + lrow <= qr) ? __expf(sB[0][r] * SCALE_F) : 0.f;
        float p1 = (kb + 16 + lrow <= qr) ? __expf(sB[1][r] * SCALE_F) : 0.f;
        lpB[r] += p0 + p1;
        Ps[640 + (kgrp * 4 + r) * 40 + lrow] = f2bf(p0);
        Ps[640 + (kgrp * 4 + r) * 40 + 16 + lrow] = f2bf(p1);
      }
    }

    // ---- O += P V (Ps is wave-private; lgkmcnt orders write->read in-wave) ----
    bf16x8 pA, pB;
    if (dA) pA = *reinterpret_cast<const bf16x8*>(&Ps[lrow * 40 + kgrp * 8]);
    if (dB) pB = *reinterpret_cast<const bf16x8*>(&Ps[640 + lrow * 40 + kgrp * 8]);
    const int cc = half * 4 + kgrp;
#pragma unroll
    for (int dt = 0; dt < 16; ++dt) {
      const int d = dt * 16 + lrow;
      bf16x8 bv = *reinterpret_cast<const bf16x8*>(&Vs[d * 64 + ((cc ^ (d & 7)) * 8)]);
      if (dA) oA[dt] = mfma16(pA, bv, oA[dt]);
      if (dB) oB[dt] = mfma16(pB, bv, oB[dt]);
    }
  }

  // ---- in-wave l reduction across the 16 column-lanes ----
#pragma unroll
  for (int r = 0; r < 4; ++r) {
#pragma unroll
    for (int m = 8; m >= 1; m >>= 1) {
      lpA[r] += __shfl_xor(lpA[r], m);
      lpB[r] += __shfl_xor(lpB[r], m);
    }
  }

  // ---- combine halves through LDS (tile A, then tile B) ----
  __syncthreads();
  if (half == 1) {
#pragma unroll
    for (int dt = 0; dt < 16; ++dt)
#pragma unroll
      for (int r = 0; r < 4; ++r)
        Obuf[(w3 * 16 + kgrp * 4 + r) * 256 + dt * 16 + lrow] = oA[dt][r];
    if (lrow == 0) {
#pragma unroll
      for (int r = 0; r < 4; ++r) Lbuf[w3 * 16 + kgrp * 4 + r] = lpA[r];
    }
  }
  __syncthreads();
  if (half == 0) {
#pragma unroll
    for (int dt = 0; dt < 16; ++dt)
#pragma unroll
      for (int r = 0; r < 4; ++r)
        oA[dt][r] += Obuf[(w3 * 16 + kgrp * 4 + r) * 256 + dt * 16 + lrow];
#pragma unroll
    for (int r = 0; r < 4; ++r) lpA[r] += Lbuf[w3 * 16 + kgrp * 4 + r];
  }
  __syncthreads();
  if (half == 1) {
#pragma unroll
    for (int dt = 0; dt < 16; ++dt)
#pragma unroll
      for (int r = 0; r < 4; ++r)
        Obuf[(w3 * 16 + kgrp * 4 + r) * 256 + dt * 16 + lrow] = oB[dt][r];
    if (lrow == 0) {
#pragma unroll
      for (int r = 0; r < 4; ++r) Lbuf[w3 * 16 + kgrp * 4 + r] = lpB[r];
    }
  }
  __syncthreads();
  if (half == 0) {
#pragma unroll
    for (int dt = 0; dt < 16; ++dt)
#pragma unroll
      for (int r = 0; r < 4; ++r)
        oB[dt][r] += Obuf[(w3 * 16 + kgrp * 4 + r) * 256 + dt * 16 + lrow];
#pragma unroll
    for (int r = 0; r < 4; ++r) lpB[r] += Lbuf[w3 * 16 + kgrp * 4 + r];

    // ---- epilogue: o/l * sigmoid(gate) ----
#pragma unroll
    for (int t = 0; t < 2; ++t) {
      const int q0 = t ? q0B : q0A;
#pragma unroll
      for (int r = 0; r < 4; ++r) {
        const int row = q0 + kgrp * 4 + r;
        const float inv_l = 1.0f / (t ? lpB[r] : lpA[r]);
        const unsigned short* grow = qkvout + (size_t)row * 9216 + h * 512 + 256;
        unsigned short* orow = og + (size_t)row * (NH * HD) + h * HD;
#pragma unroll
        for (int dt = 0; dt < 16; dt++) {
          int dim = dt * 16 + lrow;
          float g = bf2f(grow[dim]);
          float val = (t ? oB[dt][r] : oA[dt][r]) * inv_l;
          val *= 1.0f / (1.0f + __expf(-g));
          orow[dim] = f2bf(val);
        }
      }
    }
  }
}

extern "C" void kernel_launch(void* const* d_in, const int* in_sizes, int n_in,
                              void* d_out, int out_size, void* d_ws, size_t ws_size,
                              hipStream_t stream) {
  const int* positions = (const int*)d_in[0];
  const float* hidden = (const float*)d_in[1];
  const float* wq = (const float*)d_in[2];
  const float* wk = (const float*)d_in[3];
  const float* wv = (const float*)d_in[4];
  const float* wo = (const float*)d_in[5];
  const float* qnw = (const float*)d_in[6];
  const float* knw = (const float*)d_in[7];
  float* out = (float*)d_out;

  char* ws = (char*)d_ws;
  size_t off = 0;
  auto alloc = [&](size_t elems) -> unsigned short* {
    unsigned short* p = (unsigned short*)(ws + off);
    off += (elems * 2 + 255) & ~(size_t)255;
    return p;
  };
  unsigned short* hsb    = alloc((size_t)T_LEN * HID_DIM);
  unsigned short* qkvwb  = alloc((size_t)9216 * HID_DIM);
  unsigned short* wob    = alloc((size_t)HID_DIM * NH * HD);
  unsigned short* qkvout = alloc((size_t)T_LEN * 9216);
  unsigned short* qbf    = alloc((size_t)T_LEN * NH * HD);
  unsigned short* kbf    = alloc((size_t)T_LEN * NKV * HD);
  unsigned short* vTb    = alloc((size_t)NKV * HD * T_LEN);
  unsigned short* og     = alloc((size_t)T_LEN * NH * HD);

  cvt_all<<<30720, 256, 0, stream>>>(hidden, wq, wk, wv, wo, hsb, qkvwb, wob);

  gemm_bf16_bt<<<dim3(72, 16), 256, 0, stream>>>(hsb, qkvwb, qkvout, 2048, 9216, 2048, 1);

  norm_rope<<<dim3(T_LEN, NH), 256, 0, stream>>>(qkvout, qnw, positions, qbf, 9216, 512, NH * HD);
  norm_rope<<<dim3(T_LEN, NKV), 256, 0, stream>>>(qkvout + 8192, knw, positions, kbf, 9216, HD, NKV * HD);
  vtrans<<<(NKV * HD * T_LEN) / 256, 256, 0, stream>>>(qkvout, vTb, 9216, 8704);

  attn_fwd<<<dim3(16, NH), 512, 0, stream>>>(qbf, kbf, vTb, qkvout, og);

  gemm_bf16_bt<<<dim3(16, 16), 256, 0, stream>>>(og, wob, out, 2048, 2048, 4096, 0);
}

// Round 6
// 580.657 us; speedup vs baseline: 1.2803x; 1.2803x over previous
//
#include <hip/hip_runtime.h>
#include <hip/hip_bf16.h>

#define T_LEN 2048
#define HID_DIM 2048
#define NH 16
#define NKV 2
#define HD 256
#define ROT 64
#define EPS_F 1e-6f
#define SCALE_F 0.0625f   // 256^-0.5
#define THETA_F 10000000.0f

typedef __bf16 bf16x8 __attribute__((ext_vector_type(8)));
typedef float floatx4 __attribute__((ext_vector_type(4)));
typedef unsigned short ushort8v __attribute__((ext_vector_type(8)));

__device__ __forceinline__ unsigned short f2bf(float x) {
  unsigned int u = __float_as_uint(x);
  unsigned int rounding = 0x7FFFu + ((u >> 16) & 1u);
  return (unsigned short)((u + rounding) >> 16);
}
__device__ __forceinline__ float bf2f(unsigned short u) {
  return __uint_as_float(((unsigned int)u) << 16);
}
__device__ __forceinline__ floatx4 mfma16(bf16x8 a, bf16x8 b, floatx4 c) {
  return __builtin_amdgcn_mfma_f32_16x16x32_bf16(a, b, c, 0, 0, 0);
}
// async global->LDS DMA, 16B/lane (used in GEMM only; barriers drain it there by design)
__device__ __forceinline__ void gl_lds16(const unsigned short* g, unsigned short* l) {
  __builtin_amdgcn_global_load_lds(
      (const __attribute__((address_space(1))) unsigned int*)g,
      (__attribute__((address_space(3))) unsigned int*)l, 16, 0, 0);
}

// ---------------- merged fp32 -> bf16 conversion (5 segments, f4-vectorized) ----------------
__global__ __launch_bounds__(256) void cvt_all(
    const float* __restrict__ hs, const float* __restrict__ wq,
    const float* __restrict__ wk, const float* __restrict__ wv,
    const float* __restrict__ wo, unsigned short* __restrict__ hsb,
    unsigned short* __restrict__ qkvwb, unsigned short* __restrict__ wob) {
  int i = blockIdx.x * 256 + threadIdx.x;  // float4 index, total 7864320
  const float4* s4;
  ushort4* d4;
  int j;
  if (i < 1048576) { s4 = (const float4*)hs; d4 = (ushort4*)hsb; j = i; }
  else if (i < 5242880) { s4 = (const float4*)wq; d4 = (ushort4*)qkvwb; j = i - 1048576; }
  else if (i < 5505024) { s4 = (const float4*)wk; d4 = (ushort4*)qkvwb + 4194304; j = i - 5242880; }
  else if (i < 5767168) { s4 = (const float4*)wv; d4 = (ushort4*)qkvwb + 4456448; j = i - 5505024; }
  else { s4 = (const float4*)wo; d4 = (ushort4*)wob; j = i - 5767168; }
  float4 v = s4[j];
  ushort4 o;
  o.x = f2bf(v.x); o.y = f2bf(v.y); o.z = f2bf(v.z); o.w = f2bf(v.w);
  d4[j] = o;
}

// ---------------- bf16 GEMM: C[M,N] = A[M,K] * B[N,K]^T ----------------
__global__ __launch_bounds__(256) void gemm_bf16_bt(
    const unsigned short* __restrict__ A,
    const unsigned short* __restrict__ B,
    void* __restrict__ Cv, int M, int N, int K, int c_bf16) {
  __shared__ alignas(16) unsigned short As[128 * 32];
  __shared__ alignas(16) unsigned short Bs[128 * 32];
  const int tid = threadIdx.x;
  const int m0 = blockIdx.y * 128;
  const int n0 = blockIdx.x * 128;
  const int lane = tid & 63;
  const int wave = tid >> 6;
  const int wm = (wave >> 1) * 64;
  const int wn = (wave & 1) * 64;
  const int lrow = lane & 15;
  const int kgrp = lane >> 4;

  const unsigned short* aG = A + (size_t)(m0 + wave * 32 + (lane >> 2)) * K + (lane & 3) * 8;
  const unsigned short* bG = B + (size_t)(n0 + wave * 32 + (lane >> 2)) * K + (lane & 3) * 8;
  unsigned short* aL0 = &As[(wave * 32) * 32];
  unsigned short* aL1 = &As[(wave * 32 + 16) * 32];
  unsigned short* bL0 = &Bs[(wave * 32) * 32];
  unsigned short* bL1 = &Bs[(wave * 32 + 16) * 32];

  floatx4 acc[4][4];
#pragma unroll
  for (int i = 0; i < 4; i++)
#pragma unroll
    for (int j = 0; j < 4; j++) acc[i][j] = floatx4{0.f, 0.f, 0.f, 0.f};

  for (int k0 = 0; k0 < K; k0 += 32) {
    gl_lds16(aG + k0, aL0);
    gl_lds16(aG + (size_t)16 * K + k0, aL1);
    gl_lds16(bG + k0, bL0);
    gl_lds16(bG + (size_t)16 * K + k0, bL1);
    __syncthreads();
    bf16x8 af[4], bfr[4];
#pragma unroll
    for (int i = 0; i < 4; i++)
      af[i] = *reinterpret_cast<const bf16x8*>(&As[(wm + i * 16 + lrow) * 32 + kgrp * 8]);
#pragma unroll
    for (int j = 0; j < 4; j++)
      bfr[j] = *reinterpret_cast<const bf16x8*>(&Bs[(wn + j * 16 + lrow) * 32 + kgrp * 8]);
#pragma unroll
    for (int i = 0; i < 4; i++)
#pragma unroll
      for (int j = 0; j < 4; j++)
        acc[i][j] = mfma16(af[i], bfr[j], acc[i][j]);
    __syncthreads();
  }

  if (c_bf16) {
    unsigned short* C = (unsigned short*)Cv;
#pragma unroll
    for (int i = 0; i < 4; i++) {
      int row = m0 + wm + i * 16 + kgrp * 4;
#pragma unroll
      for (int j = 0; j < 4; j++) {
        int col = n0 + wn + j * 16 + lrow;
#pragma unroll
        for (int r = 0; r < 4; r++)
          C[(size_t)(row + r) * N + col] = f2bf(acc[i][j][r]);
      }
    }
  } else {
    float* C = (float*)Cv;
#pragma unroll
    for (int i = 0; i < 4; i++) {
      int row = m0 + wm + i * 16 + kgrp * 4;
#pragma unroll
      for (int j = 0; j < 4; j++) {
        int col = n0 + wn + j * 16 + lrow;
#pragma unroll
        for (int r = 0; r < 4; r++)
          C[(size_t)(row + r) * N + col] = acc[i][j][r];
      }
    }
  }
}

// ---------------- RMSNorm + partial RoPE (per (t, head), D=256) ----------------
__global__ __launch_bounds__(256) void norm_rope(
    const unsigned short* __restrict__ in, const float* __restrict__ w,
    const int* __restrict__ pos, unsigned short* __restrict__ outb,
    int in_rs, int in_hs, int out_rs) {
  const int t = blockIdx.x, h = blockIdx.y, d = threadIdx.x;
  float x = bf2f(in[(size_t)t * in_rs + h * in_hs + d]);
  float ss = x * x;
#pragma unroll
  for (int m = 32; m >= 1; m >>= 1) ss += __shfl_xor(ss, m);
  __shared__ float wsum[4];
  if ((d & 63) == 0) wsum[d >> 6] = ss;
  __syncthreads();
  float tot = (wsum[0] + wsum[1]) + (wsum[2] + wsum[3]);
  float rms = rsqrtf(tot * (1.0f / 256.0f) + EPS_F);
  float y = x * rms * (1.0f + w[d]);
  float o = y;
  if (d < ROT) {
    float partner = __shfl_xor(y, ROT / 2);
    int i = d & (ROT / 2 - 1);
    // theta^(-i/32) = 2^(-i*log2(theta)/32), log2(1e7)=23.2534966642
    float fr = (float)pos[t] * exp2f(-(float)i * (23.2534966642f / 32.0f));
    float c = cosf(fr), s = sinf(fr);
    o = (d < ROT / 2) ? (y * c - partner * s) : (partner * s + y * c);
  }
  outb[(size_t)t * out_rs + h * HD + d] = f2bf(o);
}

// ---------------- V transpose: (T, cols src_off..+512) -> (512, T) ----------------
__global__ __launch_bounds__(256) void vtrans(
    const unsigned short* __restrict__ vin, unsigned short* __restrict__ vT,
    int src_stride, int src_off) {
  int gid = blockIdx.x * 256 + threadIdx.x;  // gid = c*T + t
  int t = gid & (T_LEN - 1);
  int c = gid >> 11;
  vT[gid] = vin[(size_t)t * src_stride + src_off + c];
}

// ---------------- Flash attention v6: register-staged K/V pipeline, resident Q ----------------
// Block 512 thr (8 waves), grid (16 pairs, 16 heads). Wave (w3=wv&3, half=wv>>2):
// rows w3*16 of paired tiles (p, 31-p); half h covers 32-key chunk kb64+h*32.
// K/V(ib+1) prefetched global->VGPR right after the LDS-ready barrier of slab
// ib and committed via ds_write one full compute phase later (vmcnt wait lands
// there — latency hidden; global_load_lds DMA can't do this, every barrier
// drains it: R4 lesson). Q fragments fully resident (R5 lesson: per-slab
// reloads of a >L2 buffer = serial HBM latency + 280 MB refetch).
__global__ __launch_bounds__(512, 2) void attn_fwd(
    const unsigned short* __restrict__ qbf,    // (T, H*D) post norm+rope
    const unsigned short* __restrict__ kbf,    // (T, KV*D) post norm+rope
    const unsigned short* __restrict__ vT,     // (KV*D, T)
    const unsigned short* __restrict__ qkvout, // (T, 9216), gate at h*512+256
    unsigned short* __restrict__ og)           // (T, H*D)
{
  const int p = blockIdx.x;
  const int h = blockIdx.y;
  const int wv = threadIdx.x >> 6;
  const int w3 = wv & 3;
  const int half = wv >> 2;
  const int lane = threadIdx.x & 63;
  const int lrow = lane & 15;
  const int kgrp = lane >> 4;
  const int kvh = h >> 3;  // H/KV = 8
  const int tB = 31 - p;
  const int q0A = p * 64 + w3 * 16;
  const int q0B = tB * 64 + w3 * 16;
  const int nb = tB + 1;  // 64-key slabs

  // LDS: Ks 32KB | Vs 32KB | Ps 20KB = 84KB -> 1 block/CU, 2 waves/SIMD.
  __shared__ alignas(16) unsigned char SMEM[86016];
  unsigned short* Ks = (unsigned short*)SMEM;            // [key 0..63][256 d], chunk^=(key&7)
  unsigned short* Vs = (unsigned short*)(SMEM + 32768);  // [dim 0..255][64 k], chunk^=(dim&7)
  unsigned short* Ps = (unsigned short*)(SMEM + 65536) + wv * 1280;  // 2 tiles x 16 x 40
  float* Obuf = (float*)SMEM;
  float* Lbuf = (float*)(SMEM + 65536);

  // ---- staging address precompute ----
  const unsigned short* kgsrc[4];
  const unsigned short* vgsrc[4];
  unsigned short* kldst[4];
  unsigned short* vldst[4];
#pragma unroll
  for (int i = 0; i < 4; ++i) {
    const int inst = wv * 4 + i;
    const int key = inst * 2 + (lane >> 5);
    const int kc = lane & 31;
    kgsrc[i] = kbf + (size_t)key * (NKV * HD) + kvh * HD + kc * 8;
    kldst[i] = Ks + key * 256 + ((kc ^ (key & 7)) * 8);
    const int dim = inst * 8 + (lane >> 3);
    const int vc = lane & 7;
    vgsrc[i] = vT + (size_t)(kvh * HD + dim) * T_LEN + vc * 8;
    vldst[i] = Vs + dim * 64 + ((vc ^ (dim & 7)) * 8);
  }

  // Q fragments: both tiles fully resident (64 VGPRs; LDS caps occupancy anyway)
  bf16x8 qaA[8], qaB[8];
  {
    const unsigned short* qrA = qbf + (size_t)(q0A + lrow) * (NH * HD) + h * HD + kgrp * 8;
    const unsigned short* qrB = qbf + (size_t)(q0B + lrow) * (NH * HD) + h * HD + kgrp * 8;
#pragma unroll
    for (int s = 0; s < 8; s++) {
      qaA[s] = *reinterpret_cast<const bf16x8*>(qrA + s * 32);
      qaB[s] = *reinterpret_cast<const bf16x8*>(qrB + s * 32);
    }
  }

  float lpA[4] = {0.f, 0.f, 0.f, 0.f}, lpB[4] = {0.f, 0.f, 0.f, 0.f};
  floatx4 oA[16], oB[16];
#pragma unroll
  for (int dt = 0; dt < 16; dt++) { oA[dt] = floatx4{0.f,0.f,0.f,0.f}; oB[dt] = floatx4{0.f,0.f,0.f,0.f}; }

  // prologue: prefetch slab 0 into regs
  ushort8v kpre[4], vpre[4];
#pragma unroll
  for (int i = 0; i < 4; ++i) {
    kpre[i] = *reinterpret_cast<const ushort8v*>(kgsrc[i]);
    vpre[i] = *reinterpret_cast<const ushort8v*>(vgsrc[i]);
  }

  for (int ib = 0; ib < nb; ++ib) {
    const int kb64 = ib * 64;
    const int kb = kb64 + half * 32;  // this wave's 32-key chunk
    const bool dA = kb <= q0A + 15;
    const bool dB = kb <= q0B + 15;

    __syncthreads();  // all waves done reading Ks/Vs of slab ib-1
    // commit prefetched regs to LDS (vmcnt waits land here, ~1 compute phase after issue)
#pragma unroll
    for (int i = 0; i < 4; ++i) *reinterpret_cast<ushort8v*>(kldst[i]) = kpre[i];
#pragma unroll
    for (int i = 0; i < 4; ++i) *reinterpret_cast<ushort8v*>(vldst[i]) = vpre[i];
    __syncthreads();  // Ks/Vs(ib) ready

    // prefetch slab ib+1 (plain global loads — cross barriers freely)
    if (ib + 1 < nb) {
      const size_t ko = (size_t)(kb64 + 64) * (NKV * HD);
#pragma unroll
      for (int i = 0; i < 4; ++i) {
        kpre[i] = *reinterpret_cast<const ushort8v*>(kgsrc[i] + ko);
        vpre[i] = *reinterpret_cast<const ushort8v*>(vgsrc[i] + kb64 + 64);
      }
    }

    // ---- S = Q K^T over 2 j-subtiles of 16 keys ----
    floatx4 sA[2], sB[2];
#pragma unroll
    for (int j = 0; j < 2; j++) { sA[j] = floatx4{0.f,0.f,0.f,0.f}; sB[j] = floatx4{0.f,0.f,0.f,0.f}; }
    const unsigned short* kbase = Ks + (half * 32) * 256;
#pragma unroll
    for (int j = 0; j < 2; ++j) {
      const int ks = kb + j * 16;
      const bool nA = dA && (ks <= q0A + 15);
      const bool nB = dB && (ks <= q0B + 15);
      if (!(nA || nB)) continue;
#pragma unroll
      for (int s = 0; s < 8; s++) {
        bf16x8 kf = *reinterpret_cast<const bf16x8*>(
            &kbase[(j * 16 + lrow) * 256 + (((s * 4 + kgrp) ^ (lrow & 7)) * 8)]);
        if (nA) sA[j] = mfma16(qaA[s], kf, sA[j]);
        if (nB) sB[j] = mfma16(qaB[s], kf, sB[j]);
      }
    }

    // ---- P = exp(S*scale), causal mask, no max subtraction (|s|<=16 bounded) ----
    if (dA) {
#pragma unroll
      for (int r = 0; r < 4; ++r) {
        const int qr = q0A + kgrp * 4 + r;
        float p0 = (kb + lrow <= qr) ? __expf(sA[0][r] * SCALE_F) : 0.f;
        float p1 = (kb + 16 + lrow <= qr) ? __expf(sA[1][r] * SCALE_F) : 0.f;
        lpA[r] += p0 + p1;
        Ps[(kgrp * 4 + r) * 40 + lrow] = f2bf(p0);
        Ps[(kgrp * 4 + r) * 40 + 16 + lrow] = f2bf(p1);
      }
    }
    if (dB) {
#pragma unroll
      for (int r = 0; r < 4; ++r) {
        const int qr = q0B + kgrp * 4 + r;
        float p0 = (kb + lrow <= qr) ? __expf(sB[0][r] * SCALE_F) : 0.f;
        float p1 = (kb + 16 + lrow <= qr) ? __expf(sB[1][r] * SCALE_F) : 0.f;
        lpB[r] += p0 + p1;
        Ps[640 + (kgrp * 4 + r) * 40 + lrow] = f2bf(p0);
        Ps[640 + (kgrp * 4 + r) * 40 + 16 + lrow] = f2bf(p1);
      }
    }

    // ---- O += P V (Ps wave-private; lgkmcnt orders write->read in-wave) ----
    bf16x8 pA, pB;
    if (dA) pA = *reinterpret_cast<const bf16x8*>(&Ps[lrow * 40 + kgrp * 8]);
    if (dB) pB = *reinterpret_cast<const bf16x8*>(&Ps[640 + lrow * 40 + kgrp * 8]);
    const int cc = half * 4 + kgrp;
#pragma unroll
    for (int dt = 0; dt < 16; ++dt) {
      const int d = dt * 16 + lrow;
      bf16x8 bv = *reinterpret_cast<const bf16x8*>(&Vs[d * 64 + ((cc ^ (d & 7)) * 8)]);
      if (dA) oA[dt] = mfma16(pA, bv, oA[dt]);
      if (dB) oB[dt] = mfma16(pB, bv, oB[dt]);
    }
  }

  // ---- in-wave l reduction across the 16 column-lanes ----
#pragma unroll
  for (int r = 0; r < 4; ++r) {
#pragma unroll
    for (int m = 8; m >= 1; m >>= 1) {
      lpA[r] += __shfl_xor(lpA[r], m);
      lpB[r] += __shfl_xor(lpB[r], m);
    }
  }

  // ---- combine halves through LDS (tile A, then tile B) ----
  __syncthreads();
  if (half == 1) {
#pragma unroll
    for (int dt = 0; dt < 16; ++dt)
#pragma unroll
      for (int r = 0; r < 4; ++r)
        Obuf[(w3 * 16 + kgrp * 4 + r) * 256 + dt * 16 + lrow] = oA[dt][r];
    if (lrow == 0) {
#pragma unroll
      for (int r = 0; r < 4; ++r) Lbuf[w3 * 16 + kgrp * 4 + r] = lpA[r];
    }
  }
  __syncthreads();
  if (half == 0) {
#pragma unroll
    for (int dt = 0; dt < 16; ++dt)
#pragma unroll
      for (int r = 0; r < 4; ++r)
        oA[dt][r] += Obuf[(w3 * 16 + kgrp * 4 + r) * 256 + dt * 16 + lrow];
#pragma unroll
    for (int r = 0; r < 4; ++r) lpA[r] += Lbuf[w3 * 16 + kgrp * 4 + r];
  }
  __syncthreads();
  if (half == 1) {
#pragma unroll
    for (int dt = 0; dt < 16; ++dt)
#pragma unroll
      for (int r = 0; r < 4; ++r)
        Obuf[(w3 * 16 + kgrp * 4 + r) * 256 + dt * 16 + lrow] = oB[dt][r];
    if (lrow == 0) {
#pragma unroll
      for (int r = 0; r < 4; ++r) Lbuf[w3 * 16 + kgrp * 4 + r] = lpB[r];
    }
  }
  __syncthreads();
  if (half == 0) {
#pragma unroll
    for (int dt = 0; dt < 16; ++dt)
#pragma unroll
      for (int r = 0; r < 4; ++r)
        oB[dt][r] += Obuf[(w3 * 16 + kgrp * 4 + r) * 256 + dt * 16 + lrow];
#pragma unroll
    for (int r = 0; r < 4; ++r) lpB[r] += Lbuf[w3 * 16 + kgrp * 4 + r];

    // ---- epilogue: o/l * sigmoid(gate) ----
#pragma unroll
    for (int t = 0; t < 2; ++t) {
      const int q0 = t ? q0B : q0A;
#pragma unroll
      for (int r = 0; r < 4; ++r) {
        const int row = q0 + kgrp * 4 + r;
        const float inv_l = 1.0f / (t ? lpB[r] : lpA[r]);
        const unsigned short* grow = qkvout + (size_t)row * 9216 + h * 512 + 256;
        unsigned short* orow = og + (size_t)row * (NH * HD) + h * HD;
#pragma unroll
        for (int dt = 0; dt < 16; dt++) {
          int dim = dt * 16 + lrow;
          float g = bf2f(grow[dim]);
          float val = (t ? oB[dt][r] : oA[dt][r]) * inv_l;
          val *= 1.0f / (1.0f + __expf(-g));
          orow[dim] = f2bf(val);
        }
      }
    }
  }
}

extern "C" void kernel_launch(void* const* d_in, const int* in_sizes, int n_in,
                              void* d_out, int out_size, void* d_ws, size_t ws_size,
                              hipStream_t stream) {
  const int* positions = (const int*)d_in[0];
  const float* hidden = (const float*)d_in[1];
  const float* wq = (const float*)d_in[2];
  const float* wk = (const float*)d_in[3];
  const float* wv = (const float*)d_in[4];
  const float* wo = (const float*)d_in[5];
  const float* qnw = (const float*)d_in[6];
  const float* knw = (const float*)d_in[7];
  float* out = (float*)d_out;

  char* ws = (char*)d_ws;
  size_t off = 0;
  auto alloc = [&](size_t elems) -> unsigned short* {
    unsigned short* p = (unsigned short*)(ws + off);
    off += (elems * 2 + 255) & ~(size_t)255;
    return p;
  };
  unsigned short* hsb    = alloc((size_t)T_LEN * HID_DIM);
  unsigned short* qkvwb  = alloc((size_t)9216 * HID_DIM);
  unsigned short* wob    = alloc((size_t)HID_DIM * NH * HD);
  unsigned short* qkvout = alloc((size_t)T_LEN * 9216);
  unsigned short* qbf    = alloc((size_t)T_LEN * NH * HD);
  unsigned short* kbf    = alloc((size_t)T_LEN * NKV * HD);
  unsigned short* vTb    = alloc((size_t)NKV * HD * T_LEN);
  unsigned short* og     = alloc((size_t)T_LEN * NH * HD);

  cvt_all<<<30720, 256, 0, stream>>>(hidden, wq, wk, wv, wo, hsb, qkvwb, wob);

  gemm_bf16_bt<<<dim3(72, 16), 256, 0, stream>>>(hsb, qkvwb, qkvout, 2048, 9216, 2048, 1);

  norm_rope<<<dim3(T_LEN, NH), 256, 0, stream>>>(qkvout, qnw, positions, qbf, 9216, 512, NH * HD);
  norm_rope<<<dim3(T_LEN, NKV), 256, 0, stream>>>(qkvout + 8192, knw, positions, kbf, 9216, HD, NKV * HD);
  vtrans<<<(NKV * HD * T_LEN) / 256, 256, 0, stream>>>(qkvout, vTb, 9216, 8704);

  attn_fwd<<<dim3(16, NH), 512, 0, stream>>>(qbf, kbf, vTb, qkvout, og);

  gemm_bf16_bt<<<dim3(16, 16), 256, 0, stream>>>(og, wob, out, 2048, 2048, 4096, 0);
}

// Round 9
// 526.279 us; speedup vs baseline: 1.4126x; 1.1033x over previous
//
#include <hip/hip_runtime.h>
#include <hip/hip_bf16.h>

#define T_LEN 2048
#define HID_DIM 2048
#define NH 16
#define NKV 2
#define HD 256
#define ROT 64
#define EPS_F 1e-6f
#define SCALE_F 0.0625f   // 256^-0.5
#define THETA_F 10000000.0f

typedef __bf16 bf16x8 __attribute__((ext_vector_type(8)));
typedef float floatx4 __attribute__((ext_vector_type(4)));

__device__ __forceinline__ unsigned short f2bf(float x) {
  unsigned int u = __float_as_uint(x);
  unsigned int rounding = 0x7FFFu + ((u >> 16) & 1u);
  return (unsigned short)((u + rounding) >> 16);
}
__device__ __forceinline__ float bf2f(unsigned short u) {
  return __uint_as_float(((unsigned int)u) << 16);
}
__device__ __forceinline__ floatx4 mfma16(bf16x8 a, bf16x8 b, floatx4 c) {
  return __builtin_amdgcn_mfma_f32_16x16x32_bf16(a, b, c, 0, 0, 0);
}
// async global->LDS DMA, 16B/lane: lds dest = wave-uniform base + lane*16
__device__ __forceinline__ void gl_lds16(const unsigned short* g, unsigned short* l) {
  __builtin_amdgcn_global_load_lds(
      (const __attribute__((address_space(1))) unsigned int*)g,
      (__attribute__((address_space(3))) unsigned int*)l, 16, 0, 0);
}

// ---------------- merged fp32 -> bf16 conversion (5 segments, f4-vectorized) ----------------
__global__ __launch_bounds__(256) void cvt_all(
    const float* __restrict__ hs, const float* __restrict__ wq,
    const float* __restrict__ wk, const float* __restrict__ wv,
    const float* __restrict__ wo, unsigned short* __restrict__ hsb,
    unsigned short* __restrict__ qkvwb, unsigned short* __restrict__ wob) {
  int i = blockIdx.x * 256 + threadIdx.x;  // float4 index, total 7864320
  const float4* s4;
  ushort4* d4;
  int j;
  if (i < 1048576) { s4 = (const float4*)hs; d4 = (ushort4*)hsb; j = i; }
  else if (i < 5242880) { s4 = (const float4*)wq; d4 = (ushort4*)qkvwb; j = i - 1048576; }
  else if (i < 5505024) { s4 = (const float4*)wk; d4 = (ushort4*)qkvwb + 4194304; j = i - 5242880; }
  else if (i < 5767168) { s4 = (const float4*)wv; d4 = (ushort4*)qkvwb + 4456448; j = i - 5505024; }
  else { s4 = (const float4*)wo; d4 = (ushort4*)wob; j = i - 5767168; }
  float4 v = s4[j];
  ushort4 o;
  o.x = f2bf(v.x); o.y = f2bf(v.y); o.z = f2bf(v.z); o.w = f2bf(v.w);
  d4[j] = o;
}

// ---------------- bf16 GEMM: C[M,N] = A[M,K] * B[N,K]^T ----------------
__global__ __launch_bounds__(256) void gemm_bf16_bt(
    const unsigned short* __restrict__ A,
    const unsigned short* __restrict__ B,
    void* __restrict__ Cv, int M, int N, int K, int c_bf16) {
  __shared__ alignas(16) unsigned short As[128 * 32];
  __shared__ alignas(16) unsigned short Bs[128 * 32];
  const int tid = threadIdx.x;
  const int m0 = blockIdx.y * 128;
  const int n0 = blockIdx.x * 128;
  const int lane = tid & 63;
  const int wave = tid >> 6;
  const int wm = (wave >> 1) * 64;
  const int wn = (wave & 1) * 64;
  const int lrow = lane & 15;
  const int kgrp = lane >> 4;

  const unsigned short* aG = A + (size_t)(m0 + wave * 32 + (lane >> 2)) * K + (lane & 3) * 8;
  const unsigned short* bG = B + (size_t)(n0 + wave * 32 + (lane >> 2)) * K + (lane & 3) * 8;
  unsigned short* aL0 = &As[(wave * 32) * 32];
  unsigned short* aL1 = &As[(wave * 32 + 16) * 32];
  unsigned short* bL0 = &Bs[(wave * 32) * 32];
  unsigned short* bL1 = &Bs[(wave * 32 + 16) * 32];

  floatx4 acc[4][4];
#pragma unroll
  for (int i = 0; i < 4; i++)
#pragma unroll
    for (int j = 0; j < 4; j++) acc[i][j] = floatx4{0.f, 0.f, 0.f, 0.f};

  for (int k0 = 0; k0 < K; k0 += 32) {
    gl_lds16(aG + k0, aL0);
    gl_lds16(aG + (size_t)16 * K + k0, aL1);
    gl_lds16(bG + k0, bL0);
    gl_lds16(bG + (size_t)16 * K + k0, bL1);
    __syncthreads();
    bf16x8 af[4], bfr[4];
#pragma unroll
    for (int i = 0; i < 4; i++)
      af[i] = *reinterpret_cast<const bf16x8*>(&As[(wm + i * 16 + lrow) * 32 + kgrp * 8]);
#pragma unroll
    for (int j = 0; j < 4; j++)
      bfr[j] = *reinterpret_cast<const bf16x8*>(&Bs[(wn + j * 16 + lrow) * 32 + kgrp * 8]);
#pragma unroll
    for (int i = 0; i < 4; i++)
#pragma unroll
      for (int j = 0; j < 4; j++)
        acc[i][j] = mfma16(af[i], bfr[j], acc[i][j]);
    __syncthreads();
  }

  if (c_bf16) {
    unsigned short* C = (unsigned short*)Cv;
#pragma unroll
    for (int i = 0; i < 4; i++) {
      int row = m0 + wm + i * 16 + kgrp * 4;
#pragma unroll
      for (int j = 0; j < 4; j++) {
        int col = n0 + wn + j * 16 + lrow;
#pragma unroll
        for (int r = 0; r < 4; r++)
          C[(size_t)(row + r) * N + col] = f2bf(acc[i][j][r]);
      }
    }
  } else {
    float* C = (float*)Cv;
#pragma unroll
    for (int i = 0; i < 4; i++) {
      int row = m0 + wm + i * 16 + kgrp * 4;
#pragma unroll
      for (int j = 0; j < 4; j++) {
        int col = n0 + wn + j * 16 + lrow;
#pragma unroll
        for (int r = 0; r < 4; r++)
          C[(size_t)(row + r) * N + col] = acc[i][j][r];
      }
    }
  }
}

// ---------------- RMSNorm + partial RoPE (per (t, head), D=256) ----------------
__global__ __launch_bounds__(256) void norm_rope(
    const unsigned short* __restrict__ in, const float* __restrict__ w,
    const int* __restrict__ pos, unsigned short* __restrict__ outb,
    int in_rs, int in_hs, int out_rs) {
  const int t = blockIdx.x, h = blockIdx.y, d = threadIdx.x;
  float x = bf2f(in[(size_t)t * in_rs + h * in_hs + d]);
  float ss = x * x;
#pragma unroll
  for (int m = 32; m >= 1; m >>= 1) ss += __shfl_xor(ss, m);
  __shared__ float wsum[4];
  if ((d & 63) == 0) wsum[d >> 6] = ss;
  __syncthreads();
  float tot = (wsum[0] + wsum[1]) + (wsum[2] + wsum[3]);
  float rms = rsqrtf(tot * (1.0f / 256.0f) + EPS_F);
  float y = x * rms * (1.0f + w[d]);
  float o = y;
  if (d < ROT) {
    float partner = __shfl_xor(y, ROT / 2);
    int i = d & (ROT / 2 - 1);
    // theta^(-i/32) = 2^(-i*log2(theta)/32), log2(1e7)=23.2534966642
    float fr = (float)pos[t] * exp2f(-(float)i * (23.2534966642f / 32.0f));
    float c = cosf(fr), s = sinf(fr);
    o = (d < ROT / 2) ? (y * c - partner * s) : (partner * s + y * c);
  }
  outb[(size_t)t * out_rs + h * HD + d] = f2bf(o);
}

// ---------------- V transpose: (T, cols src_off..+512) -> (512, T) ----------------
__global__ __launch_bounds__(256) void vtrans(
    const unsigned short* __restrict__ vin, unsigned short* __restrict__ vT,
    int src_stride, int src_off) {
  int gid = blockIdx.x * 256 + threadIdx.x;  // gid = c*T + t
  int t = gid & (T_LEN - 1);
  int c = gid >> 11;
  vT[gid] = vin[(size_t)t * src_stride + src_off + c];
}

// ---------------- Flash attention (R3-proven kernel, verbatim; gate addr ported) ----------------
// No-max softmax (scores bounded: |q|,|k|<=16 after rmsnorm => |s|<=16, exp in
// fp32 range), K/V staged to LDS via global_load_lds DMA (K single-buffered,
// V double-buffered), XOR-swizzled layouts for conflict-free b128 frag reads.
// Grid (16 pairs, 16 heads), block 256 = 4 waves; wave owns 16 rows of tile p
// and 16 rows of tile 31-p (uniform total work).
__global__ __launch_bounds__(256, 1) void attn_fwd(
    const unsigned short* __restrict__ qbf,    // (T, H*D) post norm+rope
    const unsigned short* __restrict__ kbf,    // (T, KV*D) post norm+rope
    const unsigned short* __restrict__ vT,     // (KV*D, T)
    const unsigned short* __restrict__ qkvout, // (T, 9216), gate at h*512+256
    unsigned short* __restrict__ og)           // (T, H*D)
{
  const int p = blockIdx.x;
  const int h = blockIdx.y;
  const int wv = threadIdx.x >> 6;
  const int lane = threadIdx.x & 63;
  const int lrow = lane & 15;
  const int kgrp = lane >> 4;
  const int kv = h >> 3;  // H/KV = 8
  const int tB = 31 - p;
  const int q0A = p * 64 + wv * 16;
  const int q0B = tB * 64 + wv * 16;
  const int nb = tB * 2 + 2;  // block-uniform number of 32-key blocks

  // K: [key 0..31][dim chunks swizzled: pos = c ^ (key&7)], 16KB
  __shared__ alignas(16) unsigned short Ks[32 * 256];
  // V: [dim 0..255][key chunks swizzled: pos = c ^ (dim&3)], 2x16KB
  __shared__ alignas(16) unsigned short Vs[2][256 * 32];
  // P: per-wave, per-tile 16x32 bf16
  __shared__ alignas(16) unsigned short Ps[4][2][16 * 32];

  // DMA staging: wave wv handles insts [wv*4, wv*4+4) of 16 total per tile.
  auto stage_k = [&](int kb) {
#pragma unroll
    for (int i = 0; i < 4; ++i) {
      const int inst = wv * 4 + i;
      const int key_loc = inst * 2 + (lane >> 5);
      const int c = (lane & 31) ^ (key_loc & 7);
      const unsigned short* g =
          kbf + (size_t)(kb + key_loc) * (NKV * HD) + kv * HD + c * 8;
      gl_lds16(g, &Ks[inst * 512]);
    }
  };
  auto stage_v = [&](int kb, int buf) {
#pragma unroll
    for (int i = 0; i < 4; ++i) {
      const int inst = wv * 4 + i;
      const int dim = inst * 16 + (lane >> 2);
      const int c = (lane & 3) ^ (dim & 3);
      const unsigned short* g =
          vT + (size_t)(kv * HD + dim) * T_LEN + kb + c * 8;
      gl_lds16(g, &Vs[buf][inst * 512]);
    }
  };

  // Q A-fragments (global, once)
  bf16x8 qaA[8], qaB[8];
  {
    const unsigned short* qrA = qbf + (size_t)(q0A + lrow) * (NH * HD) + h * HD + kgrp * 8;
    const unsigned short* qrB = qbf + (size_t)(q0B + lrow) * (NH * HD) + h * HD + kgrp * 8;
#pragma unroll
    for (int s = 0; s < 8; s++) {
      qaA[s] = *reinterpret_cast<const bf16x8*>(qrA + s * 32);
      qaB[s] = *reinterpret_cast<const bf16x8*>(qrB + s * 32);
    }
  }

  float lpA[4] = {0.f, 0.f, 0.f, 0.f}, lpB[4] = {0.f, 0.f, 0.f, 0.f};
  floatx4 oA[16], oB[16];
#pragma unroll
  for (int dt = 0; dt < 16; dt++) { oA[dt] = floatx4{0.f,0.f,0.f,0.f}; oB[dt] = floatx4{0.f,0.f,0.f,0.f}; }

  stage_k(0);
  stage_v(0, 0);

  for (int ib = 0; ib < nb; ++ib) {
    const int kb = ib * 32;
    __syncthreads();  // drains K(ib) + V(ib) DMAs; protects V buffer reuse
    if (ib + 1 < nb) stage_v(kb + 32, (ib + 1) & 1);

    const bool dA = kb <= q0A + 15;
    const bool dB = kb <= q0B + 15;

    // ---- S = Q K^T over 2 j-subtiles of 16 keys ----
    floatx4 sA[2], sB[2];
#pragma unroll
    for (int j = 0; j < 2; j++) { sA[j] = floatx4{0.f,0.f,0.f,0.f}; sB[j] = floatx4{0.f,0.f,0.f,0.f}; }
#pragma unroll
    for (int j = 0; j < 2; ++j) {
      const int ks = kb + j * 16;
      const bool nA = dA && (ks <= q0A + 15);
      const bool nB = dB && (ks <= q0B + 15);
      if (!(nA || nB)) continue;
      bf16x8 kf[8];
#pragma unroll
      for (int s = 0; s < 8; s++)
        kf[s] = *reinterpret_cast<const bf16x8*>(
            &Ks[(j * 16 + lrow) * 256 + (((s * 4 + kgrp) ^ (lrow & 7)) * 8)]);
      if (nA) {
#pragma unroll
        for (int s = 0; s < 8; s++) sA[j] = mfma16(qaA[s], kf[s], sA[j]);
      }
      if (nB) {
#pragma unroll
        for (int s = 0; s < 8; s++) sB[j] = mfma16(qaB[s], kf[s], sB[j]);
      }
    }

    // ---- P = exp(S*scale) with causal mask (no max subtraction) ----
    if (dA) {
#pragma unroll
      for (int r = 0; r < 4; ++r) {
        const int qr = q0A + kgrp * 4 + r;
        float p0 = (kb + lrow <= qr) ? __expf(sA[0][r] * SCALE_F) : 0.f;
        float p1 = (kb + 16 + lrow <= qr) ? __expf(sA[1][r] * SCALE_F) : 0.f;
        lpA[r] += p0 + p1;
        Ps[wv][0][(kgrp * 4 + r) * 32 + lrow] = f2bf(p0);
        Ps[wv][0][(kgrp * 4 + r) * 32 + 16 + lrow] = f2bf(p1);
      }
    }
    if (dB) {
#pragma unroll
      for (int r = 0; r < 4; ++r) {
        const int qr = q0B + kgrp * 4 + r;
        float p0 = (kb + lrow <= qr) ? __expf(sB[0][r] * SCALE_F) : 0.f;
        float p1 = (kb + 16 + lrow <= qr) ? __expf(sB[1][r] * SCALE_F) : 0.f;
        lpB[r] += p0 + p1;
        Ps[wv][1][(kgrp * 4 + r) * 32 + lrow] = f2bf(p0);
        Ps[wv][1][(kgrp * 4 + r) * 32 + 16 + lrow] = f2bf(p1);
      }
    }

    __syncthreads();  // all waves done reading Ks (also drains V(ib+1) DMA)
    if (ib + 1 < nb) stage_k(kb + 32);

    // ---- O += P V ----
    bf16x8 pA, pB;
    if (dA) pA = *reinterpret_cast<const bf16x8*>(&Ps[wv][0][lrow * 32 + kgrp * 8]);
    if (dB) pB = *reinterpret_cast<const bf16x8*>(&Ps[wv][1][lrow * 32 + kgrp * 8]);
    const unsigned short* vsb = &Vs[ib & 1][0];
#pragma unroll
    for (int dt = 0; dt < 16; ++dt) {
      const int d = dt * 16 + lrow;
      bf16x8 bv = *reinterpret_cast<const bf16x8*>(
          &vsb[d * 32 + ((kgrp ^ (lrow & 3)) * 8)]);
      if (dA) oA[dt] = mfma16(pA, bv, oA[dt]);
      if (dB) oB[dt] = mfma16(pB, bv, oB[dt]);
    }
  }

  // ---- reduce l across the 16 row-lanes ----
#pragma unroll
  for (int r = 0; r < 4; ++r) {
#pragma unroll
    for (int m = 8; m >= 1; m >>= 1) {
      lpA[r] += __shfl_xor(lpA[r], m);
      lpB[r] += __shfl_xor(lpB[r], m);
    }
  }

  // ---- epilogue: o/l * sigmoid(gate) ----
#pragma unroll
  for (int t = 0; t < 2; ++t) {
    const int q0 = t ? q0B : q0A;
#pragma unroll
    for (int r = 0; r < 4; ++r) {
      const int row = q0 + kgrp * 4 + r;
      const float inv_l = 1.0f / (t ? lpB[r] : lpA[r]);
      const unsigned short* grow = qkvout + (size_t)row * 9216 + h * 512 + 256;
      unsigned short* orow = og + (size_t)row * (NH * HD) + h * HD;
#pragma unroll
      for (int dt = 0; dt < 16; dt++) {
        int dim = dt * 16 + lrow;
        float g = bf2f(grow[dim]);
        float val = (t ? oB[dt][r] : oA[dt][r]) * inv_l;
        val *= 1.0f / (1.0f + __expf(-g));
        orow[dim] = f2bf(val);
      }
    }
  }
}

extern "C" void kernel_launch(void* const* d_in, const int* in_sizes, int n_in,
                              void* d_out, int out_size, void* d_ws, size_t ws_size,
                              hipStream_t stream) {
  const int* positions = (const int*)d_in[0];
  const float* hidden = (const float*)d_in[1];
  const float* wq = (const float*)d_in[2];
  const float* wk = (const float*)d_in[3];
  const float* wv = (const float*)d_in[4];
  const float* wo = (const float*)d_in[5];
  const float* qnw = (const float*)d_in[6];
  const float* knw = (const float*)d_in[7];
  float* out = (float*)d_out;

  char* ws = (char*)d_ws;
  size_t off = 0;
  auto alloc = [&](size_t elems) -> unsigned short* {
    unsigned short* p = (unsigned short*)(ws + off);
    off += (elems * 2 + 255) & ~(size_t)255;
    return p;
  };
  unsigned short* hsb    = alloc((size_t)T_LEN * HID_DIM);
  unsigned short* qkvwb  = alloc((size_t)9216 * HID_DIM);
  unsigned short* wob    = alloc((size_t)HID_DIM * NH * HD);
  unsigned short* qkvout = alloc((size_t)T_LEN * 9216);
  unsigned short* qbf    = alloc((size_t)T_LEN * NH * HD);
  unsigned short* kbf    = alloc((size_t)T_LEN * NKV * HD);
  unsigned short* vTb    = alloc((size_t)NKV * HD * T_LEN);
  unsigned short* og     = alloc((size_t)T_LEN * NH * HD);

  cvt_all<<<30720, 256, 0, stream>>>(hidden, wq, wk, wv, wo, hsb, qkvwb, wob);

  gemm_bf16_bt<<<dim3(72, 16), 256, 0, stream>>>(hsb, qkvwb, qkvout, 2048, 9216, 2048, 1);

  norm_rope<<<dim3(T_LEN, NH), 256, 0, stream>>>(qkvout, qnw, positions, qbf, 9216, 512, NH * HD);
  norm_rope<<<dim3(T_LEN, NKV), 256, 0, stream>>>(qkvout + 8192, knw, positions, kbf, 9216, HD, NKV * HD);
  vtrans<<<(NKV * HD * T_LEN) / 256, 256, 0, stream>>>(qkvout, vTb, 9216, 8704);

  attn_fwd<<<dim3(16, NH), 256, 0, stream>>>(qbf, kbf, vTb, qkvout, og);

  gemm_bf16_bt<<<dim3(16, 16), 256, 0, stream>>>(og, wob, out, 2048, 2048, 4096, 0);
}